// Round 1
// baseline (2227.607 us; speedup 1.0000x reference)
//
#include <hip/hip_runtime.h>
#include <math.h>

// GCN 2-layer: h = Ddst^-1/2 A (Dsrc^-1/2 x) W + b, relu between.
// fp32 throughout (no fp32 MFMA on CDNA4; GEMMs on vector ALU this round).

#define F_IN  256
#define F_HID 128
#define F_CLS 40

// ---- degrees: edge-parallel atomics ----------------------------------------
__global__ void deg_kernel(const int* __restrict__ src, const int* __restrict__ dst,
                           float* __restrict__ deg_src, float* __restrict__ deg_dst, int E) {
    int i = blockIdx.x * blockDim.x + threadIdx.x;
    if (i < E) {
        atomicAdd(&deg_src[src[i]], 1.0f);
        atomicAdd(&deg_dst[dst[i]], 1.0f);
    }
}

// deg -> deg^-1/2 in place (both arrays contiguous, length 2N)
__global__ void norm_kernel(float* __restrict__ deg, int n2) {
    int i = blockIdx.x * blockDim.x + threadIdx.x;
    if (i < n2) {
        float d = deg[i];
        deg[i] = d > 0.0f ? 1.0f / sqrtf(d) : 0.0f;
    }
}

// ---- GEMM1: h1[N,128] = (X * norm_src) @ W1[256,128] -----------------------
// 64-node x 128-col tile per block, 256 threads, K chunked by 32.
__global__ __launch_bounds__(256) void gemm1_kernel(
    const float* __restrict__ X, const float* __restrict__ W1,
    const float* __restrict__ norm_src, float* __restrict__ h1, int N)
{
    __shared__ float As[64][36];    // 36: rows stay 16B-aligned, breaks pow2 stride
    __shared__ float Ws[32][128];
    const int t = threadIdx.x;
    const int node0 = blockIdx.x * 64;
    const int colg = t & 31;   // 4 cols starting at colg*4
    const int rowg = t >> 5;   // 8 nodes starting at rowg*8

    float acc[8][4] = {};

    for (int k0 = 0; k0 < F_IN; k0 += 32) {
        // A tile 64x32: 512 float4s, 2 per thread; scale by norm_src on load
        #pragma unroll
        for (int i = 0; i < 2; ++i) {
            int f = t + 256 * i;           // 0..511
            int r = f >> 3;                // 8 float4 per row
            int kk = (f & 7) << 2;
            int node = node0 + r;
            float4 v = make_float4(0.f, 0.f, 0.f, 0.f);
            float ns = 0.f;
            if (node < N) {
                v = *(const float4*)(X + (size_t)node * F_IN + k0 + kk);
                ns = norm_src[node];
            }
            As[r][kk + 0] = v.x * ns;
            As[r][kk + 1] = v.y * ns;
            As[r][kk + 2] = v.z * ns;
            As[r][kk + 3] = v.w * ns;
        }
        // W tile 32x128: 1024 float4s, 4 per thread
        #pragma unroll
        for (int i = 0; i < 4; ++i) {
            int f = t + 256 * i;           // 0..1023
            int r = f >> 5;                // 32 float4 per row
            int kk = (f & 31) << 2;
            *(float4*)&Ws[r][kk] = *(const float4*)(W1 + (size_t)(k0 + r) * F_HID + kk);
        }
        __syncthreads();

        #pragma unroll
        for (int k = 0; k < 32; ++k) {
            float w0 = Ws[k][colg * 4 + 0];
            float w1 = Ws[k][colg * 4 + 1];
            float w2 = Ws[k][colg * 4 + 2];
            float w3 = Ws[k][colg * 4 + 3];
            #pragma unroll
            for (int i = 0; i < 8; ++i) {
                float a = As[rowg * 8 + i][k];
                acc[i][0] = fmaf(a, w0, acc[i][0]);
                acc[i][1] = fmaf(a, w1, acc[i][1]);
                acc[i][2] = fmaf(a, w2, acc[i][2]);
                acc[i][3] = fmaf(a, w3, acc[i][3]);
            }
        }
        __syncthreads();
    }

    #pragma unroll
    for (int i = 0; i < 8; ++i) {
        int node = node0 + rowg * 8 + i;
        if (node < N) {
            float4 v = make_float4(acc[i][0], acc[i][1], acc[i][2], acc[i][3]);
            *(float4*)(h1 + (size_t)node * F_HID + colg * 4) = v;
        }
    }
}

// ---- SpMM1: agg1[dst] += h1[src], 128 cols, 32 threads/edge ---------------
__global__ void spmm1_kernel(const float* __restrict__ h1, const int* __restrict__ src,
                             const int* __restrict__ dst, float* __restrict__ agg1, int E) {
    int tid = blockIdx.x * blockDim.x + threadIdx.x;
    int e = tid >> 5;
    if (e >= E) return;
    int c = (tid & 31) << 2;
    int s = src[e], d = dst[e];
    const float4 v = *(const float4*)(h1 + (size_t)s * F_HID + c);
    float* o = agg1 + (size_t)d * F_HID + c;
    atomicAdd(o + 0, v.x);
    atomicAdd(o + 1, v.y);
    atomicAdd(o + 2, v.z);
    atomicAdd(o + 3, v.w);
}

// ---- GEMM2: h2[N,40] = relu(agg1*norm_dst + b1)*norm_src @ W2[128,40] ------
// whole K in LDS; 64-node tile, 320 threads (5 waves)
__global__ __launch_bounds__(320) void gemm2_kernel(
    const float* __restrict__ agg1, const float* __restrict__ W2,
    const float* __restrict__ b1, const float* __restrict__ norm_src,
    const float* __restrict__ norm_dst, float* __restrict__ h2, int N)
{
    __shared__ float As[64][132];   // 128 + 4 pad, rows 16B-aligned
    __shared__ float Ws[128][40];
    const int t = threadIdx.x;
    const int node0 = blockIdx.x * 64;

    // load full W2: 1280 float4s, 4 per thread
    #pragma unroll
    for (int i = 0; i < 4; ++i) {
        int f = t + 320 * i;      // < 1280
        int r = f / 10;
        int kk = (f % 10) * 4;
        *(float4*)&Ws[r][kk] = *(const float4*)(W2 + (size_t)r * F_CLS + kk);
    }
    // load A tile 64x128 with fused relu/bias/norm: 2048 float4s
    for (int f = t; f < 2048; f += 320) {
        int r = f >> 5;            // 32 float4 per row
        int kk = (f & 31) << 2;
        int node = node0 + r;
        float4 v = make_float4(0.f, 0.f, 0.f, 0.f);
        if (node < N) {
            float4 a = *(const float4*)(agg1 + (size_t)node * F_HID + kk);
            float nd = norm_dst[node];
            float ns = norm_src[node];
            float4 bb = *(const float4*)(b1 + kk);
            v.x = fmaxf(fmaf(a.x, nd, bb.x), 0.f) * ns;
            v.y = fmaxf(fmaf(a.y, nd, bb.y), 0.f) * ns;
            v.z = fmaxf(fmaf(a.z, nd, bb.z), 0.f) * ns;
            v.w = fmaxf(fmaf(a.w, nd, bb.w), 0.f) * ns;
        }
        *(float4*)&As[r][kk] = v;
    }
    __syncthreads();

    const int col = t % 40;
    const int rowg = t / 40;       // 0..7 -> 8 nodes each
    float acc[8] = {};
    #pragma unroll 8
    for (int k = 0; k < F_HID; ++k) {
        float w = Ws[k][col];
        #pragma unroll
        for (int i = 0; i < 8; ++i)
            acc[i] = fmaf(As[rowg * 8 + i][k], w, acc[i]);
    }
    #pragma unroll
    for (int i = 0; i < 8; ++i) {
        int node = node0 + rowg * 8 + i;
        if (node < N) h2[(size_t)node * F_CLS + col] = acc[i];
    }
}

// ---- SpMM2: out[dst] += h2[src], 40 cols, 10 threads/edge ------------------
__global__ __launch_bounds__(320) void spmm2_kernel(
    const float* __restrict__ h2, const int* __restrict__ src,
    const int* __restrict__ dst, float* __restrict__ out, int E) {
    int tid = blockIdx.x * blockDim.x + threadIdx.x;
    int e = tid / 10;
    if (e >= E) return;
    int c = (tid % 10) * 4;
    int s = src[e], d = dst[e];
    const float4 v = *(const float4*)(h2 + (size_t)s * F_CLS + c);
    float* o = out + (size_t)d * F_CLS + c;
    atomicAdd(o + 0, v.x);
    atomicAdd(o + 1, v.y);
    atomicAdd(o + 2, v.z);
    atomicAdd(o + 3, v.w);
}

// ---- final epilogue: out = out*norm_dst + b2 -------------------------------
__global__ void epi_kernel(float* __restrict__ out, const float* __restrict__ norm_dst,
                           const float* __restrict__ b2, int total) {
    int i = blockIdx.x * blockDim.x + threadIdx.x;
    if (i < total) {
        int n = i / F_CLS;
        int c = i % F_CLS;
        out[i] = fmaf(out[i], norm_dst[n], b2[c]);
    }
}

extern "C" void kernel_launch(void* const* d_in, const int* in_sizes, int n_in,
                              void* d_out, int out_size, void* d_ws, size_t ws_size,
                              hipStream_t stream) {
    const float* X   = (const float*)d_in[0];
    const int*   src = (const int*)d_in[1];
    const int*   dst = (const int*)d_in[2];
    const float* W1  = (const float*)d_in[3];
    const float* b1  = (const float*)d_in[4];
    const float* W2  = (const float*)d_in[5];
    const float* b2  = (const float*)d_in[6];
    float* out = (float*)d_out;

    const int N = in_sizes[0] / F_IN;
    const int E = in_sizes[1];

    float* ws       = (float*)d_ws;
    float* norm_src = ws;                        // N  (deg then norm, in place)
    float* norm_dst = ws + N;                    // N
    float* h1       = ws + 2 * (size_t)N;        // N*128
    float* agg1     = h1 + (size_t)N * F_HID;    // N*128
    float* h2       = agg1 + (size_t)N * F_HID;  // N*40

    // zero what gets accumulated into (ws/out are poisoned 0xAA each call)
    hipMemsetAsync(norm_src, 0, 2 * (size_t)N * sizeof(float), stream);
    hipMemsetAsync(agg1, 0, (size_t)N * F_HID * sizeof(float), stream);
    hipMemsetAsync(out, 0, (size_t)N * F_CLS * sizeof(float), stream);

    deg_kernel<<<(E + 255) / 256, 256, 0, stream>>>(src, dst, norm_src, norm_dst, E);
    norm_kernel<<<(2 * N + 255) / 256, 256, 0, stream>>>(norm_src, 2 * N);

    gemm1_kernel<<<(N + 63) / 64, 256, 0, stream>>>(X, W1, norm_src, h1, N);

    {
        long long threads = (long long)E * 32;
        spmm1_kernel<<<(unsigned)((threads + 255) / 256), 256, 0, stream>>>(h1, src, dst, agg1, E);
    }

    gemm2_kernel<<<(N + 63) / 64, 320, 0, stream>>>(agg1, W2, b1, norm_src, norm_dst, h2, N);

    {
        long long threads = (long long)E * 10;
        spmm2_kernel<<<(unsigned)((threads + 319) / 320), 320, 0, stream>>>(h2, src, dst, out, E);
    }

    {
        int total = N * F_CLS;
        epi_kernel<<<(total + 255) / 256, 256, 0, stream>>>(out, norm_dst, b2, total);
    }
}

// Round 2
// 501.857 us; speedup vs baseline: 4.4387x; 4.4387x over previous
//
#include <hip/hip_runtime.h>
#include <math.h>

// GCN 2-layer: h = Ddst^-1/2 A (Dsrc^-1/2 x) W + b, relu between.
// R2: CSR-based SpMM (no fp32 atomics — R1 showed 16B/atomic HBM writeback,
// 1.6GB writes for a 51MB output). CSR built per-call: count -> scan -> scatter.

#define F_IN  256
#define F_HID 128
#define F_CLS 40

// ---- int degree counts -----------------------------------------------------
__global__ void count_kernel(const int* __restrict__ src, const int* __restrict__ dst,
                             int* __restrict__ cnt_src, int* __restrict__ cnt_dst, int E) {
    int i = blockIdx.x * blockDim.x + threadIdx.x;
    if (i < E) {
        atomicAdd(&cnt_src[src[i]], 1);
        atomicAdd(&cnt_dst[dst[i]], 1);
    }
}

// counts -> deg^-1/2 (0 if deg==0)
__global__ void norm_kernel(const int* __restrict__ cnt_src, const int* __restrict__ cnt_dst,
                            float* __restrict__ norm_src, float* __restrict__ norm_dst, int N) {
    int i = blockIdx.x * blockDim.x + threadIdx.x;
    if (i < N) {
        int cs = cnt_src[i], cd = cnt_dst[i];
        norm_src[i] = cs > 0 ? 1.0f / sqrtf((float)cs) : 0.0f;
        norm_dst[i] = cd > 0 ? 1.0f / sqrtf((float)cd) : 0.0f;
    }
}

// ---- hierarchical exclusive scan over cnt_dst (1024 elems / block) ---------
__global__ __launch_bounds__(256) void scan1_kernel(const int* __restrict__ cnt,
                                                    int* __restrict__ row_off,
                                                    int* __restrict__ blk_sums, int N) {
    __shared__ int s[256];
    const int t = threadIdx.x;
    const int base = blockIdx.x * 1024 + t * 4;
    int v0 = (base + 0 < N) ? cnt[base + 0] : 0;
    int v1 = (base + 1 < N) ? cnt[base + 1] : 0;
    int v2 = (base + 2 < N) ? cnt[base + 2] : 0;
    int v3 = (base + 3 < N) ? cnt[base + 3] : 0;
    int local = v0 + v1 + v2 + v3;
    s[t] = local;
    __syncthreads();
    for (int off = 1; off < 256; off <<= 1) {
        int x = (t >= off) ? s[t - off] : 0;
        __syncthreads();
        s[t] += x;
        __syncthreads();
    }
    int excl = s[t] - local;
    if (t == 255) blk_sums[blockIdx.x] = s[t];
    if (base + 0 < N) row_off[base + 0] = excl;
    if (base + 1 < N) row_off[base + 1] = excl + v0;
    if (base + 2 < N) row_off[base + 2] = excl + v0 + v1;
    if (base + 3 < N) row_off[base + 3] = excl + v0 + v1 + v2;
}

__global__ __launch_bounds__(256) void scan2_kernel(int* __restrict__ blk_sums, int B) {
    __shared__ int s[256];
    const int t = threadIdx.x;
    int local = (t < B) ? blk_sums[t] : 0;
    s[t] = local;
    __syncthreads();
    for (int off = 1; off < 256; off <<= 1) {
        int x = (t >= off) ? s[t - off] : 0;
        __syncthreads();
        s[t] += x;
        __syncthreads();
    }
    if (t < B) blk_sums[t] = s[t] - local;   // exclusive
}

__global__ __launch_bounds__(256) void scan3_kernel(int* __restrict__ row_off,
                                                    int* __restrict__ cursor,
                                                    const int* __restrict__ blk_sums,
                                                    int N, int E) {
    const int t = threadIdx.x;
    const int base = blockIdx.x * 1024 + t * 4;
    const int add = blk_sums[blockIdx.x];
    #pragma unroll
    for (int i = 0; i < 4; ++i) {
        int idx = base + i;
        if (idx < N) {
            int v = row_off[idx] + add;
            row_off[idx] = v;
            cursor[idx] = v;
        }
    }
    if (blockIdx.x == 0 && t == 0) row_off[N] = E;
}

// ---- scatter edges into CSR (grouped by dst) -------------------------------
__global__ void scatter_kernel(const int* __restrict__ src, const int* __restrict__ dst,
                               int* __restrict__ cursor, int* __restrict__ csr_src, int E) {
    int e = blockIdx.x * blockDim.x + threadIdx.x;
    if (e < E) {
        int pos = atomicAdd(&cursor[dst[e]], 1);
        csr_src[pos] = src[e];
    }
}

// ---- GEMM1: h1[N,128] = (X * norm_src) @ W1[256,128] -----------------------
__global__ __launch_bounds__(256) void gemm1_kernel(
    const float* __restrict__ X, const float* __restrict__ W1,
    const float* __restrict__ norm_src, float* __restrict__ h1, int N)
{
    __shared__ float As[64][36];
    __shared__ float Ws[32][128];
    const int t = threadIdx.x;
    const int node0 = blockIdx.x * 64;
    const int colg = t & 31;
    const int rowg = t >> 5;

    float acc[8][4] = {};

    for (int k0 = 0; k0 < F_IN; k0 += 32) {
        #pragma unroll
        for (int i = 0; i < 2; ++i) {
            int f = t + 256 * i;
            int r = f >> 3;
            int kk = (f & 7) << 2;
            int node = node0 + r;
            float4 v = make_float4(0.f, 0.f, 0.f, 0.f);
            float ns = 0.f;
            if (node < N) {
                v = *(const float4*)(X + (size_t)node * F_IN + k0 + kk);
                ns = norm_src[node];
            }
            As[r][kk + 0] = v.x * ns;
            As[r][kk + 1] = v.y * ns;
            As[r][kk + 2] = v.z * ns;
            As[r][kk + 3] = v.w * ns;
        }
        #pragma unroll
        for (int i = 0; i < 4; ++i) {
            int f = t + 256 * i;
            int r = f >> 5;
            int kk = (f & 31) << 2;
            *(float4*)&Ws[r][kk] = *(const float4*)(W1 + (size_t)(k0 + r) * F_HID + kk);
        }
        __syncthreads();

        #pragma unroll
        for (int k = 0; k < 32; ++k) {
            float w0 = Ws[k][colg * 4 + 0];
            float w1 = Ws[k][colg * 4 + 1];
            float w2 = Ws[k][colg * 4 + 2];
            float w3 = Ws[k][colg * 4 + 3];
            #pragma unroll
            for (int i = 0; i < 8; ++i) {
                float a = As[rowg * 8 + i][k];
                acc[i][0] = fmaf(a, w0, acc[i][0]);
                acc[i][1] = fmaf(a, w1, acc[i][1]);
                acc[i][2] = fmaf(a, w2, acc[i][2]);
                acc[i][3] = fmaf(a, w3, acc[i][3]);
            }
        }
        __syncthreads();
    }

    #pragma unroll
    for (int i = 0; i < 8; ++i) {
        int node = node0 + rowg * 8 + i;
        if (node < N) {
            float4 v = make_float4(acc[i][0], acc[i][1], acc[i][2], acc[i][3]);
            *(float4*)(h1 + (size_t)node * F_HID + colg * 4) = v;
        }
    }
}

// ---- SpMM1 (CSR): agg1[n,:] = sum_{e in row n} h1[csr_src[e],:] ------------
// 256 threads = 8 groups of 32; one group per node; 4 cols per lane.
__global__ __launch_bounds__(256) void spmm1_csr_kernel(
    const float* __restrict__ h1, const int* __restrict__ row_off,
    const int* __restrict__ csr_src, float* __restrict__ agg1, int N)
{
    const int t = threadIdx.x;
    const int node = blockIdx.x * 8 + (t >> 5);
    if (node >= N) return;
    const int c = (t & 31) << 2;
    const int start = row_off[node];
    const int end = row_off[node + 1];
    float4 acc = make_float4(0.f, 0.f, 0.f, 0.f);
    for (int j = start; j < end; ++j) {
        int s = csr_src[j];
        float4 v = *(const float4*)(h1 + (size_t)s * F_HID + c);
        acc.x += v.x; acc.y += v.y; acc.z += v.z; acc.w += v.w;
    }
    *(float4*)(agg1 + (size_t)node * F_HID + c) = acc;
}

// ---- GEMM2: h2[N,40] = relu(agg1*norm_dst + b1)*norm_src @ W2[128,40] ------
__global__ __launch_bounds__(320) void gemm2_kernel(
    const float* __restrict__ agg1, const float* __restrict__ W2,
    const float* __restrict__ b1, const float* __restrict__ norm_src,
    const float* __restrict__ norm_dst, float* __restrict__ h2, int N)
{
    __shared__ float As[64][132];
    __shared__ float Ws[128][40];
    const int t = threadIdx.x;
    const int node0 = blockIdx.x * 64;

    #pragma unroll
    for (int i = 0; i < 4; ++i) {
        int f = t + 320 * i;
        int r = f / 10;
        int kk = (f % 10) * 4;
        *(float4*)&Ws[r][kk] = *(const float4*)(W2 + (size_t)r * F_CLS + kk);
    }
    for (int f = t; f < 2048; f += 320) {
        int r = f >> 5;
        int kk = (f & 31) << 2;
        int node = node0 + r;
        float4 v = make_float4(0.f, 0.f, 0.f, 0.f);
        if (node < N) {
            float4 a = *(const float4*)(agg1 + (size_t)node * F_HID + kk);
            float nd = norm_dst[node];
            float ns = norm_src[node];
            float4 bb = *(const float4*)(b1 + kk);
            v.x = fmaxf(fmaf(a.x, nd, bb.x), 0.f) * ns;
            v.y = fmaxf(fmaf(a.y, nd, bb.y), 0.f) * ns;
            v.z = fmaxf(fmaf(a.z, nd, bb.z), 0.f) * ns;
            v.w = fmaxf(fmaf(a.w, nd, bb.w), 0.f) * ns;
        }
        *(float4*)&As[r][kk] = v;
    }
    __syncthreads();

    const int col = t % 40;
    const int rowg = t / 40;
    float acc[8] = {};
    #pragma unroll 8
    for (int k = 0; k < F_HID; ++k) {
        float w = Ws[k][col];
        #pragma unroll
        for (int i = 0; i < 8; ++i)
            acc[i] = fmaf(As[rowg * 8 + i][k], w, acc[i]);
    }
    #pragma unroll
    for (int i = 0; i < 8; ++i) {
        int node = node0 + rowg * 8 + i;
        if (node < N) h2[(size_t)node * F_CLS + col] = acc[i];
    }
}

// ---- SpMM2 (CSR) + epilogue: out[n,:] = (sum h2[src,:])*norm_dst[n] + b2 ---
// 256 threads = 16 groups of 16; lanes 0..9 cover 40 cols as float4.
__global__ __launch_bounds__(256) void spmm2_csr_kernel(
    const float* __restrict__ h2, const int* __restrict__ row_off,
    const int* __restrict__ csr_src, const float* __restrict__ norm_dst,
    const float* __restrict__ b2, float* __restrict__ out, int N)
{
    const int t = threadIdx.x;
    const int node = blockIdx.x * 16 + (t >> 4);
    const int lane = t & 15;
    if (node >= N || lane >= 10) return;
    const int c = lane << 2;
    const int start = row_off[node];
    const int end = row_off[node + 1];
    float4 acc = make_float4(0.f, 0.f, 0.f, 0.f);
    for (int j = start; j < end; ++j) {
        int s = csr_src[j];
        float4 v = *(const float4*)(h2 + (size_t)s * F_CLS + c);
        acc.x += v.x; acc.y += v.y; acc.z += v.z; acc.w += v.w;
    }
    float nd = norm_dst[node];
    float4 bb = *(const float4*)(b2 + c);
    float4 r;
    r.x = fmaf(acc.x, nd, bb.x);
    r.y = fmaf(acc.y, nd, bb.y);
    r.z = fmaf(acc.z, nd, bb.z);
    r.w = fmaf(acc.w, nd, bb.w);
    *(float4*)(out + (size_t)node * F_CLS + c) = r;
}

extern "C" void kernel_launch(void* const* d_in, const int* in_sizes, int n_in,
                              void* d_out, int out_size, void* d_ws, size_t ws_size,
                              hipStream_t stream) {
    const float* X   = (const float*)d_in[0];
    const int*   src = (const int*)d_in[1];
    const int*   dst = (const int*)d_in[2];
    const float* W1  = (const float*)d_in[3];
    const float* b1  = (const float*)d_in[4];
    const float* W2  = (const float*)d_in[5];
    const float* b2  = (const float*)d_in[6];
    float* out = (float*)d_out;

    const int N = in_sizes[0] / F_IN;
    const int E = in_sizes[1];
    const int NB = (N + 1023) / 1024;   // scan blocks (must be <= 256)

    // workspace layout (all 4-byte elems)
    char* w = (char*)d_ws;
    int*   cnt_src  = (int*)w;                      w += (size_t)N * 4;
    int*   cnt_dst  = (int*)w;                      w += (size_t)N * 4;
    int*   row_off  = (int*)w;                      w += (size_t)(N + 1) * 4;
    int*   cursor   = (int*)w;                      w += (size_t)N * 4;
    int*   blk_sums = (int*)w;                      w += 256 * 4;
    int*   csr_src  = (int*)w;                      w += (size_t)E * 4;
    float* norm_src = (float*)w;                    w += (size_t)N * 4;
    float* norm_dst = (float*)w;                    w += (size_t)N * 4;
    float* h1       = (float*)w;                    w += (size_t)N * F_HID * 4;
    float* agg1     = (float*)w;                    w += (size_t)N * F_HID * 4;
    float* h2       = (float*)w;                    w += (size_t)N * F_CLS * 4;

    hipMemsetAsync(cnt_src, 0, 2 * (size_t)N * sizeof(int), stream);  // cnt_src + cnt_dst

    count_kernel<<<(E + 255) / 256, 256, 0, stream>>>(src, dst, cnt_src, cnt_dst, E);
    norm_kernel<<<(N + 255) / 256, 256, 0, stream>>>(cnt_src, cnt_dst, norm_src, norm_dst, N);

    scan1_kernel<<<NB, 256, 0, stream>>>(cnt_dst, row_off, blk_sums, N);
    scan2_kernel<<<1, 256, 0, stream>>>(blk_sums, NB);
    scan3_kernel<<<NB, 256, 0, stream>>>(row_off, cursor, blk_sums, N, E);
    scatter_kernel<<<(E + 255) / 256, 256, 0, stream>>>(src, dst, cursor, csr_src, E);

    gemm1_kernel<<<(N + 63) / 64, 256, 0, stream>>>(X, W1, norm_src, h1, N);

    spmm1_csr_kernel<<<(N + 7) / 8, 256, 0, stream>>>(h1, row_off, csr_src, agg1, N);

    gemm2_kernel<<<(N + 63) / 64, 320, 0, stream>>>(agg1, W2, b1, norm_src, norm_dst, h2, N);

    spmm2_csr_kernel<<<(N + 15) / 16, 256, 0, stream>>>(h2, row_off, csr_src, norm_dst, b2, out, N);
}

// Round 3
// 442.439 us; speedup vs baseline: 5.0348x; 1.1343x over previous
//
#include <hip/hip_runtime.h>
#include <hip/hip_bf16.h>
#include <math.h>

// GCN 2-layer: h = Ddst^-1/2 A (Dsrc^-1/2 x) W + b, relu between.
// R3: GEMM1 via bf16 MFMA (16x16x32), h1 stored bf16 (halves SpMM1 gather).
// CSR SpMM from R2 retained (R1: fp32 atomics = 16B/op HBM writeback).

#define F_IN  256
#define F_HID 128
#define F_CLS 40

typedef __bf16 bf16_t;
typedef bf16_t bf16x8 __attribute__((ext_vector_type(8)));
typedef float floatx4 __attribute__((ext_vector_type(4)));

static __device__ __forceinline__ unsigned short f2b(float f) {
    __hip_bfloat16 h = __float2bfloat16(f);   // RNE
    return __builtin_bit_cast(unsigned short, h);
}
static __device__ __forceinline__ float b2f(unsigned short u) {
    return __uint_as_float((unsigned)u << 16);
}

// ---- int degree counts -----------------------------------------------------
__global__ void count_kernel(const int* __restrict__ src, const int* __restrict__ dst,
                             int* __restrict__ cnt_src, int* __restrict__ cnt_dst, int E) {
    int i = blockIdx.x * blockDim.x + threadIdx.x;
    if (i < E) {
        atomicAdd(&cnt_src[src[i]], 1);
        atomicAdd(&cnt_dst[dst[i]], 1);
    }
}

// counts -> deg^-1/2 (0 if deg==0)
__global__ void norm_kernel(const int* __restrict__ cnt_src, const int* __restrict__ cnt_dst,
                            float* __restrict__ norm_src, float* __restrict__ norm_dst, int N) {
    int i = blockIdx.x * blockDim.x + threadIdx.x;
    if (i < N) {
        int cs = cnt_src[i], cd = cnt_dst[i];
        norm_src[i] = cs > 0 ? 1.0f / sqrtf((float)cs) : 0.0f;
        norm_dst[i] = cd > 0 ? 1.0f / sqrtf((float)cd) : 0.0f;
    }
}

// ---- hierarchical exclusive scan over cnt_dst (1024 elems / block) ---------
__global__ __launch_bounds__(256) void scan1_kernel(const int* __restrict__ cnt,
                                                    int* __restrict__ row_off,
                                                    int* __restrict__ blk_sums, int N) {
    __shared__ int s[256];
    const int t = threadIdx.x;
    const int base = blockIdx.x * 1024 + t * 4;
    int v0 = (base + 0 < N) ? cnt[base + 0] : 0;
    int v1 = (base + 1 < N) ? cnt[base + 1] : 0;
    int v2 = (base + 2 < N) ? cnt[base + 2] : 0;
    int v3 = (base + 3 < N) ? cnt[base + 3] : 0;
    int local = v0 + v1 + v2 + v3;
    s[t] = local;
    __syncthreads();
    for (int off = 1; off < 256; off <<= 1) {
        int x = (t >= off) ? s[t - off] : 0;
        __syncthreads();
        s[t] += x;
        __syncthreads();
    }
    int excl = s[t] - local;
    if (t == 255) blk_sums[blockIdx.x] = s[t];
    if (base + 0 < N) row_off[base + 0] = excl;
    if (base + 1 < N) row_off[base + 1] = excl + v0;
    if (base + 2 < N) row_off[base + 2] = excl + v0 + v1;
    if (base + 3 < N) row_off[base + 3] = excl + v0 + v1 + v2;
}

__global__ __launch_bounds__(256) void scan2_kernel(int* __restrict__ blk_sums, int B) {
    __shared__ int s[256];
    const int t = threadIdx.x;
    int local = (t < B) ? blk_sums[t] : 0;
    s[t] = local;
    __syncthreads();
    for (int off = 1; off < 256; off <<= 1) {
        int x = (t >= off) ? s[t - off] : 0;
        __syncthreads();
        s[t] += x;
        __syncthreads();
    }
    if (t < B) blk_sums[t] = s[t] - local;   // exclusive
}

__global__ __launch_bounds__(256) void scan3_kernel(int* __restrict__ row_off,
                                                    int* __restrict__ cursor,
                                                    const int* __restrict__ blk_sums,
                                                    int N, int E) {
    const int t = threadIdx.x;
    const int base = blockIdx.x * 1024 + t * 4;
    const int add = blk_sums[blockIdx.x];
    #pragma unroll
    for (int i = 0; i < 4; ++i) {
        int idx = base + i;
        if (idx < N) {
            int v = row_off[idx] + add;
            row_off[idx] = v;
            cursor[idx] = v;
        }
    }
    if (blockIdx.x == 0 && t == 0) row_off[N] = E;
}

// ---- scatter edges into CSR (grouped by dst) -------------------------------
__global__ void scatter_kernel(const int* __restrict__ src, const int* __restrict__ dst,
                               int* __restrict__ cursor, int* __restrict__ csr_src, int E) {
    int e = blockIdx.x * blockDim.x + threadIdx.x;
    if (e < E) {
        int pos = atomicAdd(&cursor[dst[e]], 1);
        csr_src[pos] = src[e];
    }
}

// ---- pack W1 [256][128] fp32 -> W1t [128][256] bf16 (n-major, k contig) ----
__global__ __launch_bounds__(256) void pack_w1t_kernel(const float* __restrict__ W1,
                                                       __hip_bfloat16* __restrict__ W1t) {
    int idx = blockIdx.x * 256 + threadIdx.x;     // 32768 total
    int n = idx >> 8;
    int k = idx & 255;
    W1t[idx] = __float2bfloat16(W1[(size_t)k * F_HID + n]);
}

// ---- GEMM1 (MFMA): h1b[N,128] = bf16( (X*norm_src)bf16 @ W1bf16 ) ----------
// 256 thr = 4 waves. BM=64 (16 rows/wave), BN=128, BK=64 (4 chunks of K=256).
__global__ __launch_bounds__(256) void gemm1_mfma_kernel(
    const float* __restrict__ X, const __hip_bfloat16* __restrict__ W1t,
    const float* __restrict__ norm_src, __hip_bfloat16* __restrict__ h1b, int N)
{
    __shared__ __hip_bfloat16 As[64][72];    // +8 pad: row stride 144B -> bank shift 4
    __shared__ __hip_bfloat16 Bs[128][72];
    const int t = threadIdx.x;
    const int node0 = blockIdx.x * 64;
    const int lane = t & 63;
    const int w = t >> 6;
    const int l15 = lane & 15;
    const int quad = lane >> 4;

    floatx4 acc[8] = {};

    for (int k0 = 0; k0 < F_IN; k0 += 64) {
        // stage A: 64 rows x 64 cols fp32 -> bf16*norm, 4 float4 per thread
        #pragma unroll
        for (int i = 0; i < 4; ++i) {
            int f = t + 256 * i;          // 0..1023
            int r = f >> 4;               // 16 float4 per row
            int cseg = (f & 15) << 2;
            int node = node0 + r;
            float4 v = make_float4(0.f, 0.f, 0.f, 0.f);
            float ns = 0.f;
            if (node < N) {
                v = *(const float4*)(X + (size_t)node * F_IN + k0 + cseg);
                ns = norm_src[node];
            }
            ushort4 pk;
            pk.x = f2b(v.x * ns);
            pk.y = f2b(v.y * ns);
            pk.z = f2b(v.z * ns);
            pk.w = f2b(v.w * ns);
            *(ushort4*)&As[r][cseg] = pk;
        }
        // stage B: W1t rows n=0..127, 64 bf16 each -> 4 x 16B per thread
        #pragma unroll
        for (int i = 0; i < 4; ++i) {
            int f = t + 256 * i;          // 0..1023
            int n = f >> 3;               // 8 x 16B chunks per row
            int seg = (f & 7) << 3;       // bf16 units
            *(uint4*)&Bs[n][seg] = *(const uint4*)(W1t + (size_t)n * F_IN + k0 + seg);
        }
        __syncthreads();

        const int arow = w * 16 + l15;
        #pragma unroll
        for (int ks = 0; ks < 2; ++ks) {
            bf16x8 a = *(const bf16x8*)&As[arow][ks * 32 + quad * 8];
            #pragma unroll
            for (int nt = 0; nt < 8; ++nt) {
                bf16x8 b = *(const bf16x8*)&Bs[nt * 16 + l15][ks * 32 + quad * 8];
                acc[nt] = __builtin_amdgcn_mfma_f32_16x16x32_bf16(a, b, acc[nt], 0, 0, 0);
            }
        }
        __syncthreads();
    }

    // C/D: col = lane&15, row = quad*4 + reg
    #pragma unroll
    for (int nt = 0; nt < 8; ++nt) {
        #pragma unroll
        for (int r = 0; r < 4; ++r) {
            int node = node0 + w * 16 + quad * 4 + r;
            if (node < N)
                h1b[(size_t)node * F_HID + nt * 16 + l15] = __float2bfloat16(acc[nt][r]);
        }
    }
}

// ---- SpMM1 (CSR, bf16 gather): agg1[n,:] = sum h1b[csr_src,:] --------------
__global__ __launch_bounds__(256) void spmm1_csr_kernel(
    const __hip_bfloat16* __restrict__ h1b, const int* __restrict__ row_off,
    const int* __restrict__ csr_src, float* __restrict__ agg1, int N)
{
    const int t = threadIdx.x;
    const int node = blockIdx.x * 8 + (t >> 5);
    if (node >= N) return;
    const int c = (t & 31) << 2;
    const int start = row_off[node];
    const int end = row_off[node + 1];
    float4 acc = make_float4(0.f, 0.f, 0.f, 0.f);
    for (int j = start; j < end; ++j) {
        int s = csr_src[j];
        ushort4 u = *(const ushort4*)(h1b + (size_t)s * F_HID + c);
        acc.x += b2f(u.x);
        acc.y += b2f(u.y);
        acc.z += b2f(u.z);
        acc.w += b2f(u.w);
    }
    *(float4*)(agg1 + (size_t)node * F_HID + c) = acc;
}

// ---- GEMM2: h2[N,40] = relu(agg1*norm_dst + b1)*norm_src @ W2[128,40] ------
__global__ __launch_bounds__(320) void gemm2_kernel(
    const float* __restrict__ agg1, const float* __restrict__ W2,
    const float* __restrict__ b1, const float* __restrict__ norm_src,
    const float* __restrict__ norm_dst, float* __restrict__ h2, int N)
{
    __shared__ float As[64][132];
    __shared__ float Ws[128][40];
    const int t = threadIdx.x;
    const int node0 = blockIdx.x * 64;

    #pragma unroll
    for (int i = 0; i < 4; ++i) {
        int f = t + 320 * i;
        int r = f / 10;
        int kk = (f % 10) * 4;
        *(float4*)&Ws[r][kk] = *(const float4*)(W2 + (size_t)r * F_CLS + kk);
    }
    for (int f = t; f < 2048; f += 320) {
        int r = f >> 5;
        int kk = (f & 31) << 2;
        int node = node0 + r;
        float4 v = make_float4(0.f, 0.f, 0.f, 0.f);
        if (node < N) {
            float4 a = *(const float4*)(agg1 + (size_t)node * F_HID + kk);
            float nd = norm_dst[node];
            float ns = norm_src[node];
            float4 bb = *(const float4*)(b1 + kk);
            v.x = fmaxf(fmaf(a.x, nd, bb.x), 0.f) * ns;
            v.y = fmaxf(fmaf(a.y, nd, bb.y), 0.f) * ns;
            v.z = fmaxf(fmaf(a.z, nd, bb.z), 0.f) * ns;
            v.w = fmaxf(fmaf(a.w, nd, bb.w), 0.f) * ns;
        }
        *(float4*)&As[r][kk] = v;
    }
    __syncthreads();

    const int col = t % 40;
    const int rowg = t / 40;
    float acc[8] = {};
    #pragma unroll 8
    for (int k = 0; k < F_HID; ++k) {
        float w = Ws[k][col];
        #pragma unroll
        for (int i = 0; i < 8; ++i)
            acc[i] = fmaf(As[rowg * 8 + i][k], w, acc[i]);
    }
    #pragma unroll
    for (int i = 0; i < 8; ++i) {
        int node = node0 + rowg * 8 + i;
        if (node < N) h2[(size_t)node * F_CLS + col] = acc[i];
    }
}

// ---- SpMM2 (CSR) + epilogue: out[n,:] = (sum h2[src,:])*norm_dst[n] + b2 ---
__global__ __launch_bounds__(256) void spmm2_csr_kernel(
    const float* __restrict__ h2, const int* __restrict__ row_off,
    const int* __restrict__ csr_src, const float* __restrict__ norm_dst,
    const float* __restrict__ b2, float* __restrict__ out, int N)
{
    const int t = threadIdx.x;
    const int node = blockIdx.x * 16 + (t >> 4);
    const int lane = t & 15;
    if (node >= N || lane >= 10) return;
    const int c = lane << 2;
    const int start = row_off[node];
    const int end = row_off[node + 1];
    float4 acc = make_float4(0.f, 0.f, 0.f, 0.f);
    for (int j = start; j < end; ++j) {
        int s = csr_src[j];
        float4 v = *(const float4*)(h2 + (size_t)s * F_CLS + c);
        acc.x += v.x; acc.y += v.y; acc.z += v.z; acc.w += v.w;
    }
    float nd = norm_dst[node];
    float4 bb = *(const float4*)(b2 + c);
    float4 r;
    r.x = fmaf(acc.x, nd, bb.x);
    r.y = fmaf(acc.y, nd, bb.y);
    r.z = fmaf(acc.z, nd, bb.z);
    r.w = fmaf(acc.w, nd, bb.w);
    *(float4*)(out + (size_t)node * F_CLS + c) = r;
}

extern "C" void kernel_launch(void* const* d_in, const int* in_sizes, int n_in,
                              void* d_out, int out_size, void* d_ws, size_t ws_size,
                              hipStream_t stream) {
    const float* X   = (const float*)d_in[0];
    const int*   src = (const int*)d_in[1];
    const int*   dst = (const int*)d_in[2];
    const float* W1  = (const float*)d_in[3];
    const float* b1  = (const float*)d_in[4];
    const float* W2  = (const float*)d_in[5];
    const float* b2  = (const float*)d_in[6];
    float* out = (float*)d_out;

    const int N = in_sizes[0] / F_IN;
    const int E = in_sizes[1];
    const int NB = (N + 1023) / 1024;   // scan blocks (<= 256)

    // workspace layout — keep every array 16B-aligned
    char* w = (char*)d_ws;
    int*   cnt_src  = (int*)w;                      w += (size_t)N * 4;
    int*   cnt_dst  = (int*)w;                      w += (size_t)N * 4;
    int*   row_off  = (int*)w;                      w += (size_t)(N + 4) * 4;
    int*   cursor   = (int*)w;                      w += (size_t)N * 4;
    int*   blk_sums = (int*)w;                      w += 256 * 4;
    int*   csr_src  = (int*)w;                      w += (size_t)E * 4;
    float* norm_src = (float*)w;                    w += (size_t)N * 4;
    float* norm_dst = (float*)w;                    w += (size_t)N * 4;
    float* agg1     = (float*)w;                    w += (size_t)N * F_HID * 4;
    float* h2       = (float*)w;                    w += (size_t)N * F_CLS * 4;
    __hip_bfloat16* W1t = (__hip_bfloat16*)w;       w += (size_t)F_HID * F_IN * 2;
    __hip_bfloat16* h1b = (__hip_bfloat16*)w;       w += (size_t)N * F_HID * 2;

    hipMemsetAsync(cnt_src, 0, 2 * (size_t)N * sizeof(int), stream);  // cnt_src + cnt_dst

    count_kernel<<<(E + 255) / 256, 256, 0, stream>>>(src, dst, cnt_src, cnt_dst, E);
    norm_kernel<<<(N + 255) / 256, 256, 0, stream>>>(cnt_src, cnt_dst, norm_src, norm_dst, N);

    scan1_kernel<<<NB, 256, 0, stream>>>(cnt_dst, row_off, blk_sums, N);
    scan2_kernel<<<1, 256, 0, stream>>>(blk_sums, NB);
    scan3_kernel<<<NB, 256, 0, stream>>>(row_off, cursor, blk_sums, N, E);
    scatter_kernel<<<(E + 255) / 256, 256, 0, stream>>>(src, dst, cursor, csr_src, E);

    pack_w1t_kernel<<<(F_HID * F_IN) / 256, 256, 0, stream>>>(W1, W1t);

    gemm1_mfma_kernel<<<(N + 63) / 64, 256, 0, stream>>>(X, W1t, norm_src, h1b, N);

    spmm1_csr_kernel<<<(N + 7) / 8, 256, 0, stream>>>(h1b, row_off, csr_src, agg1, N);

    gemm2_kernel<<<(N + 63) / 64, 320, 0, stream>>>(agg1, W2, b1, norm_src, norm_dst, h2, N);

    spmm2_csr_kernel<<<(N + 15) / 16, 256, 0, stream>>>(h2, row_off, csr_src, norm_dst, b2, out, N);
}